// Round 9
// baseline (579.211 us; speedup 1.0000x reference)
//
#include <hip/hip_runtime.h>

#define NB 256   // blocks for hist/scatter passes
#define ND 256   // digit buckets

// ---------------- pass A: per-block digit histograms for BOTH sides ----------------
__global__ __launch_bounds__(256) void k_hist2(const int* __restrict__ src, const int* __restrict__ dst,
                                               int* __restrict__ hist_u, int* __restrict__ hist_m,
                                               int E, int chunk) {
    __shared__ int hu[ND], hm[ND];
    for (int t = threadIdx.x; t < ND; t += 256) { hu[t] = 0; hm[t] = 0; }
    __syncthreads();
    int b = blockIdx.x;
    int e0 = b * chunk, e1 = min(E, e0 + chunk);
    for (int e = e0 + threadIdx.x; e < e1; e += 256) {
        atomicAdd(&hu[src[e] >> 9], 1);
        atomicAdd(&hm[dst[e] >> 7], 1);
    }
    __syncthreads();
    for (int t = threadIdx.x; t < ND; t += 256) {
        hist_u[t * NB + b] = hu[t];   // digit-major layout -> flat scan gives scatter bases
        hist_m[t * NB + b] = hm[t];
    }
}

// ---------------- 2-level inclusive scan -> exclusive offsets ----------------
__global__ void k_scan_local(const int* __restrict__ deg, int* __restrict__ scanned,
                             int* __restrict__ bsums, int N) {
    __shared__ int s[1024];
    int base = blockIdx.x * 1024;
    for (int t = threadIdx.x; t < 1024; t += 256) {
        int i = base + t;
        s[t] = (i < N) ? deg[i] : 0;
    }
    __syncthreads();
    for (int d = 1; d < 1024; d <<= 1) {
        int vals[4];
        for (int j = 0; j < 4; ++j) {
            int t = threadIdx.x + j * 256;
            vals[j] = (t >= d) ? s[t - d] : 0;
        }
        __syncthreads();
        for (int j = 0; j < 4; ++j) {
            int t = threadIdx.x + j * 256;
            s[t] += vals[j];
        }
        __syncthreads();
    }
    for (int t = threadIdx.x; t < 1024; t += 256) {
        int i = base + t;
        if (i < N) scanned[i] = s[t];
    }
    if (threadIdx.x == 0) bsums[blockIdx.x] = s[1023];
}

__global__ void k_scan_carry(int* bsums, int nb) {
    __shared__ int s[256];
    int t = threadIdx.x;
    s[t] = (t < nb) ? bsums[t] : 0;
    __syncthreads();
    for (int d = 1; d < 256; d <<= 1) {
        int v = (t >= d) ? s[t - d] : 0;
        __syncthreads();
        s[t] += v;
        __syncthreads();
    }
    if (t < nb) bsums[t] = s[t];
}

__global__ void k_scan_off(const int* __restrict__ scanned, const int* __restrict__ bsums,
                           int* __restrict__ off, int N) {
    int i = blockIdx.x * 256 + threadIdx.x;
    if (i > N) return;
    int v = 0;
    if (i > 0) {
        int j = i - 1;
        int b = j >> 10;
        v = scanned[j] + (b > 0 ? bsums[b - 1] : 0);
    }
    off[i] = v;
}

// ---------------- pass A scatter: partition edges by top digit (no global atomics) ----------------
__global__ __launch_bounds__(256) void k_scatter(const int* __restrict__ key, const int* __restrict__ val,
                                                 const int* __restrict__ off_flat, int2* __restrict__ tmp,
                                                 int E, int chunk, int shift) {
    __shared__ int cnt[ND];
    for (int t = threadIdx.x; t < ND; t += 256) cnt[t] = 0;
    __syncthreads();
    int b = blockIdx.x;
    int e0 = b * chunk, e1 = min(E, e0 + chunk);
    for (int e = e0 + threadIdx.x; e < e1; e += 256) {
        int k = key[e];
        int d = k >> shift;
        int r = atomicAdd(&cnt[d], 1);           // LDS-only rank
        tmp[off_flat[d * NB + b] + r] = make_int2(k, val[e]);
    }
}

// ---------------- pass B: per-bucket counting sort -> adj + node offsets ----------------
template <int WIDTH>
__global__ __launch_bounds__(256) void k_bucket(const int2* __restrict__ tmp,
                                                const int* __restrict__ off_flat,
                                                int* __restrict__ adj, int* __restrict__ off_node,
                                                int E, int shift, int NN) {
    __shared__ int cnt[WIDTH];
    int d = blockIdx.x;
    int bstart = off_flat[d * NB];
    int bend   = off_flat[(d + 1) * NB];         // off_flat has ND*NB+1 entries; last == E
    for (int t = threadIdx.x; t < WIDTH; t += 256) cnt[t] = 0;
    __syncthreads();
    int bsz = bend - bstart;
    for (int i = threadIdx.x; i < bsz; i += 256)
        atomicAdd(&cnt[tmp[bstart + i].x & (WIDTH - 1)], 1);
    __syncthreads();
    // exclusive scan of cnt[0..WIDTH) by wave 0
    int lane = threadIdx.x;
    if (lane < 64) {
        constexpr int EPL = WIDTH >> 6;
        int vals[EPL];
        int tot = 0;
        #pragma unroll
        for (int j = 0; j < EPL; ++j) { vals[j] = cnt[lane * EPL + j]; tot += vals[j]; }
        int inc = tot;
        #pragma unroll
        for (int o = 1; o < 64; o <<= 1) {
            int tsh = __shfl_up(inc, o, 64);
            if (lane >= o) inc += tsh;
        }
        int ex = inc - tot;
        #pragma unroll
        for (int j = 0; j < EPL; ++j) { cnt[lane * EPL + j] = ex; ex += vals[j]; }
    }
    __syncthreads();
    // emit node offsets (deg = off[n+1]-off[n] downstream)
    int base_node = d << shift;
    for (int t = threadIdx.x; t < WIDTH; t += 256) {
        int node = base_node + t;
        if (node < NN) off_node[node] = bstart + cnt[t];
    }
    if (d == 0 && threadIdx.x == 0) off_node[NN] = E;
    __syncthreads();
    // scatter within bucket
    for (int i = threadIdx.x; i < bsz; i += 256) {
        int2 e = tmp[bstart + i];
        int r = atomicAdd(&cnt[e.x & (WIDTH - 1)], 1);
        adj[bstart + r] = e.y;
    }
}

// ---------------- movie projection: relu(movie_x @ proj_w + b), transposed weights ----------------
__global__ __launch_bounds__(256, 2) void k_proj(const float* __restrict__ mx,
                                                 const float* __restrict__ w,
                                                 const float* __restrict__ b,
                                                 float* __restrict__ out, int M) {
    __shared__ float4 wt[64 * 64];      // wt[k4*64+lane] = {w[4k4+j][lane]}, 64 KB
    __shared__ float xs[16][256];       // 16 KB
    for (int t = threadIdx.x; t < 4096; t += 256) {
        int lane_i = t & 63, k4 = t >> 6, kb = k4 * 4;
        wt[t] = make_float4(w[(kb + 0) * 64 + lane_i], w[(kb + 1) * 64 + lane_i],
                            w[(kb + 2) * 64 + lane_i], w[(kb + 3) * 64 + lane_i]);
    }
    __syncthreads();
    int wid = threadIdx.x >> 6, lane = threadIdx.x & 63;
    int r0 = wid * 4;
    float bias = b[lane];
    for (int n0 = blockIdx.x * 16; n0 < M; n0 += gridDim.x * 16) {
        // wave-private staging of own 4 rows (no cross-wave barrier needed)
        #pragma unroll
        for (int rr = 0; rr < 4; ++rr) {
            int n = n0 + r0 + rr;
            if (n < M)
                ((float4*)&xs[r0 + rr][0])[lane] = ((const float4*)mx)[(size_t)n * 64 + lane];
        }
        float a0 = bias, a1 = bias, a2 = bias, a3 = bias;
        #pragma unroll 2
        for (int k4 = 0; k4 < 64; ++k4) {
            float4 wv = wt[k4 * 64 + lane];
            float4 x0 = *(const float4*)&xs[r0 + 0][k4 * 4];
            float4 x1 = *(const float4*)&xs[r0 + 1][k4 * 4];
            float4 x2 = *(const float4*)&xs[r0 + 2][k4 * 4];
            float4 x3 = *(const float4*)&xs[r0 + 3][k4 * 4];
            #pragma unroll
            for (int j = 0; j < 4; ++j) {
                float wvj = (&wv.x)[j];
                a0 += (&x0.x)[j] * wvj;
                a1 += (&x1.x)[j] * wvj;
                a2 += (&x2.x)[j] * wvj;
                a3 += (&x3.x)[j] * wvj;
            }
        }
        int n = n0 + r0;
        if (n + 0 < M) out[(size_t)(n + 0) * 64 + lane] = fmaxf(a0, 0.f);
        if (n + 1 < M) out[(size_t)(n + 1) * 64 + lane] = fmaxf(a1, 0.f);
        if (n + 2 < M) out[(size_t)(n + 2) * 64 + lane] = fmaxf(a2, 0.f);
        if (n + 3 < M) out[(size_t)(n + 3) * 64 + lane] = fmaxf(a3, 0.f);
    }
}

// ---------------- gather-side segment mean: one wave per node, 4 rows in flight ----------------
__global__ __launch_bounds__(256) void k_agg(const float* __restrict__ x,
                                             const int* __restrict__ adj,
                                             const int* __restrict__ off,
                                             float* __restrict__ out, int N) {
    int node = blockIdx.x * 4 + (threadIdx.x >> 6);
    if (node >= N) return;
    int lane = threadIdx.x & 63;
    int g = lane >> 4, i = lane & 15;
    int s0 = off[node], s1 = off[node + 1];
    float4 a = make_float4(0.f, 0.f, 0.f, 0.f);
    float4 b = make_float4(0.f, 0.f, 0.f, 0.f);
    int e = s0 + g;
    for (; e + 4 < s1; e += 8) {
        float4 v = ((const float4*)x)[(size_t)adj[e] * 16 + i];
        float4 w = ((const float4*)x)[(size_t)adj[e + 4] * 16 + i];
        a.x += v.x; a.y += v.y; a.z += v.z; a.w += v.w;
        b.x += w.x; b.y += w.y; b.z += w.z; b.w += w.w;
    }
    if (e < s1) {
        float4 v = ((const float4*)x)[(size_t)adj[e] * 16 + i];
        a.x += v.x; a.y += v.y; a.z += v.z; a.w += v.w;
    }
    a.x += b.x; a.y += b.y; a.z += b.z; a.w += b.w;
    #pragma unroll
    for (int o = 16; o <= 32; o <<= 1) {
        a.x += __shfl_xor(a.x, o, 64);
        a.y += __shfl_xor(a.y, o, 64);
        a.z += __shfl_xor(a.z, o, 64);
        a.w += __shfl_xor(a.w, o, 64);
    }
    int deg = s1 - s0;
    float scale = (deg > 0) ? 1.0f / (float)deg : 0.f;
    if (g == 0) {
        float4 r = make_float4(a.x * scale, a.y * scale, a.z * scale, a.w * scale);
        ((float4*)out)[(size_t)node * 16 + i] = r;
    }
}

// ---------------- layer-1 transform + relu + residual; 8 nodes/wave ----------------
// res = self + relu(mean @ wl + bl + self @ wr)
__global__ __launch_bounds__(256, 4) void k_trans1(const float* __restrict__ mean,
                                                   const float* __restrict__ self,
                                                   const float* __restrict__ wl,
                                                   const float* __restrict__ bl,
                                                   const float* __restrict__ wr,
                                                   float* __restrict__ res, int N) {
    __shared__ float4 wlt[1024], wrt[1024];    // transposed weights, 32 KB
    __shared__ float ms[32][64], ss[32][64];   // 32 KB (wave-private 8-row slices)
    for (int t = threadIdx.x; t < 1024; t += 256) {
        int lane_i = t & 63, k4 = t >> 6, kb = k4 * 4;
        wlt[t] = make_float4(wl[(kb + 0) * 64 + lane_i], wl[(kb + 1) * 64 + lane_i],
                             wl[(kb + 2) * 64 + lane_i], wl[(kb + 3) * 64 + lane_i]);
        wrt[t] = make_float4(wr[(kb + 0) * 64 + lane_i], wr[(kb + 1) * 64 + lane_i],
                             wr[(kb + 2) * 64 + lane_i], wr[(kb + 3) * 64 + lane_i]);
    }
    __syncthreads();
    int wid = threadIdx.x >> 6, lane = threadIdx.x & 63;
    int r0 = wid * 8;
    int q = lane >> 4, c = lane & 15;
    float bias = bl[lane];
    for (int n0 = blockIdx.x * 32; n0 < N; n0 += gridDim.x * 32) {
        // wave-private staging: each 16-lane group stages 2 of the wave's 8 rows
        #pragma unroll
        for (int h = 0; h < 2; ++h) {
            int rr = q + h * 4;
            int n = n0 + r0 + rr;
            if (n < N) {
                ((float4*)&ms[r0 + rr][0])[c] = ((const float4*)mean)[(size_t)n * 16 + c];
                ((float4*)&ss[r0 + rr][0])[c] = ((const float4*)self)[(size_t)n * 16 + c];
            }
        }
        float a[8];
        #pragma unroll
        for (int nn = 0; nn < 8; ++nn) a[nn] = bias;
        #pragma unroll 1
        for (int k4 = 0; k4 < 16; ++k4) {
            float4 wlv = wlt[k4 * 64 + lane];
            float4 wrv = wrt[k4 * 64 + lane];
            #pragma unroll
            for (int nn = 0; nn < 8; ++nn) {
                float4 mv = *(const float4*)&ms[r0 + nn][k4 * 4];
                float4 sv = *(const float4*)&ss[r0 + nn][k4 * 4];
                a[nn] += mv.x * wlv.x + sv.x * wrv.x;
                a[nn] += mv.y * wlv.y + sv.y * wrv.y;
                a[nn] += mv.z * wlv.z + sv.z * wrv.z;
                a[nn] += mv.w * wlv.w + sv.w * wrv.w;
            }
        }
        int n = n0 + r0;
        #pragma unroll
        for (int nn = 0; nn < 8; ++nn)
            if (n + nn < N)
                res[(size_t)(n + nn) * 64 + lane] = ss[r0 + nn][lane] + fmaxf(a[nn], 0.f);
    }
}

// ---------------- layer-2 transform + l2norm + decoder half-projection; 8 nodes/wave ----------------
// u2 = mean @ wl + bl + res @ wr ; A = (u2 @ wd) / max(||u2||, 1e-12)
// wd read from GLOBAL (L1-hot) to fit LDS in 64 KB.
// NOTE: outA may alias mean (in-place, row-exclusive) -> no __restrict__ on those.
__global__ __launch_bounds__(256, 4) void k_trans2(const float* mean,
                                                   const float* __restrict__ res,
                                                   const float* wl, const float* bl,
                                                   const float* wr, const float* wd,
                                                   float* outA, int N) {
    __shared__ float4 wlt[1024], wrt[1024];    // 32 KB
    __shared__ float ms[32][64], ss[32][64];   // 32 KB; ms reused for raw u2
    for (int t = threadIdx.x; t < 1024; t += 256) {
        int lane_i = t & 63, k4 = t >> 6, kb = k4 * 4;
        wlt[t] = make_float4(wl[(kb + 0) * 64 + lane_i], wl[(kb + 1) * 64 + lane_i],
                             wl[(kb + 2) * 64 + lane_i], wl[(kb + 3) * 64 + lane_i]);
        wrt[t] = make_float4(wr[(kb + 0) * 64 + lane_i], wr[(kb + 1) * 64 + lane_i],
                             wr[(kb + 2) * 64 + lane_i], wr[(kb + 3) * 64 + lane_i]);
    }
    __syncthreads();
    int wid = threadIdx.x >> 6, lane = threadIdx.x & 63;
    int r0 = wid * 8;
    int q = lane >> 4, c = lane & 15;
    float bias = bl[lane];
    for (int n0 = blockIdx.x * 32; n0 < N; n0 += gridDim.x * 32) {
        #pragma unroll
        for (int h = 0; h < 2; ++h) {
            int rr = q + h * 4;
            int n = n0 + r0 + rr;
            if (n < N) {
                ((float4*)&ms[r0 + rr][0])[c] = ((const float4*)mean)[(size_t)n * 16 + c];
                ((float4*)&ss[r0 + rr][0])[c] = ((const float4*)res)[(size_t)n * 16 + c];
            }
        }
        float a[8];
        #pragma unroll
        for (int nn = 0; nn < 8; ++nn) a[nn] = bias;
        #pragma unroll 1
        for (int k4 = 0; k4 < 16; ++k4) {
            float4 wlv = wlt[k4 * 64 + lane];
            float4 wrv = wrt[k4 * 64 + lane];
            #pragma unroll
            for (int nn = 0; nn < 8; ++nn) {
                float4 mv = *(const float4*)&ms[r0 + nn][k4 * 4];
                float4 sv = *(const float4*)&ss[r0 + nn][k4 * 4];
                a[nn] += mv.x * wlv.x + sv.x * wrv.x;
                a[nn] += mv.y * wlv.y + sv.y * wrv.y;
                a[nn] += mv.z * wlv.z + sv.z * wrv.z;
                a[nn] += mv.w * wlv.w + sv.w * wrv.w;
            }
        }
        // per-node ||u2||^2 via wave-wide xor reduce; then overwrite own ms rows with raw u2
        float sc[8];
        #pragma unroll
        for (int nn = 0; nn < 8; ++nn) {
            float qq = a[nn] * a[nn];
            #pragma unroll
            for (int o = 1; o < 64; o <<= 1) qq += __shfl_xor(qq, o, 64);
            sc[nn] = 1.f / fmaxf(sqrtf(qq), 1e-12f);
            ms[r0 + nn][lane] = a[nn];
        }
        float b[8];
        #pragma unroll
        for (int nn = 0; nn < 8; ++nn) b[nn] = 0.f;
        #pragma unroll 2
        for (int k4 = 0; k4 < 16; ++k4) {
            int kb = k4 * 4;
            float4 wv = make_float4(wd[(kb + 0) * 64 + lane], wd[(kb + 1) * 64 + lane],
                                    wd[(kb + 2) * 64 + lane], wd[(kb + 3) * 64 + lane]);
            #pragma unroll
            for (int nn = 0; nn < 8; ++nn) {
                float4 tv = *(const float4*)&ms[r0 + nn][kb];
                b[nn] += tv.x * wv.x + tv.y * wv.y + tv.z * wv.z + tv.w * wv.w;
            }
        }
        int n = n0 + r0;
        #pragma unroll
        for (int nn = 0; nn < 8; ++nn)
            if (n + nn < N)
                outA[(size_t)(n + nn) * 64 + lane] = b[nn] * sc[nn];
    }
}

// ---------------- decoder: out = relu(A[ls]+B[ld]+b1) . w2 + b2  (4 edges/wave) ----------------
__global__ __launch_bounds__(256) void k_dec(const float* __restrict__ A,
                                             const float* __restrict__ B,
                                             const int* __restrict__ ls,
                                             const int* __restrict__ ld,
                                             const float* __restrict__ b1,
                                             const float* __restrict__ w2,
                                             const float* __restrict__ b2,
                                             float* __restrict__ out, int EL) {
    int lane = threadIdx.x & 63;
    int g = lane >> 4, i = lane & 15;
    int e = blockIdx.x * 16 + (threadIdx.x >> 6) * 4 + g;
    if (e >= EL) return;
    int u = ls[e], m = ld[e];
    float4 av  = ((const float4*)A)[(size_t)u * 16 + i];
    float4 bv  = ((const float4*)B)[(size_t)m * 16 + i];
    float4 b1v = ((const float4*)b1)[i];
    float4 w2v = ((const float4*)w2)[i];
    float p = fmaxf(av.x + bv.x + b1v.x, 0.f) * w2v.x
            + fmaxf(av.y + bv.y + b1v.y, 0.f) * w2v.y
            + fmaxf(av.z + bv.z + b1v.z, 0.f) * w2v.z
            + fmaxf(av.w + bv.w + b1v.w, 0.f) * w2v.w;
    #pragma unroll
    for (int o = 1; o <= 8; o <<= 1) p += __shfl_xor(p, o, 64);
    if (i == 0) out[e] = p + b2[0];
}

extern "C" void kernel_launch(void* const* d_in, const int* in_sizes, int n_in,
                              void* d_out, int out_size, void* d_ws, size_t ws_size,
                              hipStream_t stream) {
    const float* movie_x  = (const float*)d_in[0];
    const float* user_emb = (const float*)d_in[1];
    const float* proj_w   = (const float*)d_in[2];
    const float* proj_b   = (const float*)d_in[3];
    const float* c1_um_wl = (const float*)d_in[4];
    const float* c1_um_bl = (const float*)d_in[5];
    const float* c1_um_wr = (const float*)d_in[6];
    const float* c1_mu_wl = (const float*)d_in[7];
    const float* c1_mu_bl = (const float*)d_in[8];
    const float* c1_mu_wr = (const float*)d_in[9];
    const float* c2_um_wl = (const float*)d_in[10];
    const float* c2_um_bl = (const float*)d_in[11];
    const float* c2_um_wr = (const float*)d_in[12];
    const float* c2_mu_wl = (const float*)d_in[13];
    const float* c2_mu_bl = (const float*)d_in[14];
    const float* c2_mu_wr = (const float*)d_in[15];
    const float* dec_w1   = (const float*)d_in[16];
    const float* dec_b1   = (const float*)d_in[17];
    const float* dec_w2   = (const float*)d_in[18];
    const float* dec_b2   = (const float*)d_in[19];
    const int* edge_src = (const int*)d_in[20];
    const int* edge_dst = (const int*)d_in[21];
    const int* lbl_src  = (const int*)d_in[22];
    const int* lbl_dst  = (const int*)d_in[23];

    const int M  = in_sizes[0] / 256;
    const int U  = in_sizes[1] / 64;
    const int E  = in_sizes[20];
    const int EL = in_sizes[22];
    float* out = (float*)d_out;

    char* ws = (char*)d_ws;
    size_t off = 0;
    auto alloc = [&](size_t bytes) -> void* {
        off = (off + 255) & ~(size_t)255;
        void* p = ws + off;
        off += bytes;
        return p;
    };
    int* bsums  = (int*)alloc(1024);
    int* off_u  = (int*)alloc((size_t)(U + 1) * 4);
    int* off_m  = (int*)alloc((size_t)(M + 1) * 4);
    int* adj_u  = (int*)alloc((size_t)E * 4);
    int* adj_m  = (int*)alloc((size_t)E * 4);
    float* movie0 = (float*)alloc((size_t)M * 64 * 4);   // later reused as B
    float* mean_m = (float*)alloc((size_t)M * 64 * 4);
    float* mean_u = (float*)alloc((size_t)U * 64 * 4);   // later reused as A (in-place)
    float* m_res  = (float*)alloc((size_t)M * 64 * 4);
    float* u_res  = (float*)alloc((size_t)U * 64 * 4);

    // CSR-build scratch aliases (all dead before mean_m/mean_u first written):
    int*  hist_u   = (int*)mean_m;            // ND*NB ints = 256 KB
    int*  hist_m   = hist_u + ND * NB;        // 256 KB
    int*  scanned  = hist_m + ND * NB;        // 256 KB
    int*  off_flat = scanned + ND * NB;       // ND*NB+1 ints
    int2* tmp      = (int2*)mean_u;           // E*8 = 16 MB (< 25.6 MB)

    auto cdiv = [](int a, int b) { return (a + b - 1) / b; };
    const int chunk = cdiv(E, NB);
    const int NF = ND * NB;                   // 65536 flat counters

    hipMemsetAsync(hist_u, 0, (size_t)NF * 4, stream);
    hipMemsetAsync(hist_m, 0, (size_t)NF * 4, stream);
    k_hist2<<<NB, 256, 0, stream>>>(edge_src, edge_dst, hist_u, hist_m, E, chunk);

    // movie-side CSR (bucket by dst>>7, width 128)
    k_scan_local<<<NF / 1024, 256, 0, stream>>>(hist_m, scanned, bsums, NF);
    k_scan_carry<<<1, 256, 0, stream>>>(bsums, NF / 1024);
    k_scan_off<<<cdiv(NF + 1, 256), 256, 0, stream>>>(scanned, bsums, off_flat, NF);
    k_scatter<<<NB, 256, 0, stream>>>(edge_dst, edge_src, off_flat, tmp, E, chunk, 7);
    k_bucket<128><<<ND, 256, 0, stream>>>(tmp, off_flat, adj_m, off_m, E, 7, M);

    // user-side CSR (bucket by src>>9, width 512)
    k_scan_local<<<NF / 1024, 256, 0, stream>>>(hist_u, scanned, bsums, NF);
    k_scan_carry<<<1, 256, 0, stream>>>(bsums, NF / 1024);
    k_scan_off<<<cdiv(NF + 1, 256), 256, 0, stream>>>(scanned, bsums, off_flat, NF);
    k_scatter<<<NB, 256, 0, stream>>>(edge_src, edge_dst, off_flat, tmp, E, chunk, 9);
    k_bucket<512><<<ND, 256, 0, stream>>>(tmp, off_flat, adj_u, off_u, E, 9, U);

    k_proj<<<cdiv(M, 16), 256, 0, stream>>>(movie_x, proj_w, proj_b, movie0, M);

    int gt_u = min(cdiv(U, 32), 2048);
    int gt_m = min(cdiv(M, 32), 2048);

    // layer 1
    k_agg<<<cdiv(M, 4), 256, 0, stream>>>(user_emb, adj_m, off_m, mean_m, M);
    k_agg<<<cdiv(U, 4), 256, 0, stream>>>(movie0, adj_u, off_u, mean_u, U);
    k_trans1<<<gt_m, 256, 0, stream>>>(mean_m, movie0, c1_um_wl, c1_um_bl, c1_um_wr, m_res, M);
    k_trans1<<<gt_u, 256, 0, stream>>>(mean_u, user_emb, c1_mu_wl, c1_mu_bl, c1_mu_wr, u_res, U);

    // layer 2
    k_agg<<<cdiv(M, 4), 256, 0, stream>>>(u_res, adj_m, off_m, mean_m, M);
    k_agg<<<cdiv(U, 4), 256, 0, stream>>>(m_res, adj_u, off_u, mean_u, U);
    // B = l2norm(m2) @ W1_bot   (into movie0 buffer)
    k_trans2<<<gt_m, 256, 0, stream>>>(mean_m, m_res, c2_um_wl, c2_um_bl, c2_um_wr,
                                       dec_w1 + 64 * 64, movie0, M);
    // A = l2norm(u2) @ W1_top   (in-place into mean_u)
    k_trans2<<<gt_u, 256, 0, stream>>>(mean_u, u_res, c2_mu_wl, c2_mu_bl, c2_mu_wr,
                                       dec_w1, mean_u, U);

    // decoder
    k_dec<<<cdiv(EL, 16), 256, 0, stream>>>(mean_u, movie0, lbl_src, lbl_dst,
                                            dec_b1, dec_w2, dec_b2, out, EL);
}

// Round 10
// 515.903 us; speedup vs baseline: 1.1227x; 1.1227x over previous
//
#include <hip/hip_runtime.h>

#define NB 256   // blocks for hist/scatter passes
#define ND 256   // digit buckets

typedef _Float16 f16x8 __attribute__((ext_vector_type(8)));
typedef _Float16 f16x2 __attribute__((ext_vector_type(2)));
typedef float f32x4 __attribute__((ext_vector_type(4)));

// ---------------- pass A: per-block digit histograms for BOTH sides ----------------
__global__ __launch_bounds__(256) void k_hist2(const int* __restrict__ src, const int* __restrict__ dst,
                                               int* __restrict__ hist_u, int* __restrict__ hist_m,
                                               int E, int chunk) {
    __shared__ int hu[ND], hm[ND];
    for (int t = threadIdx.x; t < ND; t += 256) { hu[t] = 0; hm[t] = 0; }
    __syncthreads();
    int b = blockIdx.x;
    int e0 = b * chunk, e1 = min(E, e0 + chunk);
    for (int e = e0 + threadIdx.x; e < e1; e += 256) {
        atomicAdd(&hu[src[e] >> 9], 1);
        atomicAdd(&hm[dst[e] >> 7], 1);
    }
    __syncthreads();
    for (int t = threadIdx.x; t < ND; t += 256) {
        hist_u[t * NB + b] = hu[t];
        hist_m[t * NB + b] = hm[t];
    }
}

// ---------------- 2-level inclusive scan -> exclusive offsets ----------------
__global__ void k_scan_local(const int* __restrict__ deg, int* __restrict__ scanned,
                             int* __restrict__ bsums, int N) {
    __shared__ int s[1024];
    int base = blockIdx.x * 1024;
    for (int t = threadIdx.x; t < 1024; t += 256) {
        int i = base + t;
        s[t] = (i < N) ? deg[i] : 0;
    }
    __syncthreads();
    for (int d = 1; d < 1024; d <<= 1) {
        int vals[4];
        for (int j = 0; j < 4; ++j) {
            int t = threadIdx.x + j * 256;
            vals[j] = (t >= d) ? s[t - d] : 0;
        }
        __syncthreads();
        for (int j = 0; j < 4; ++j) {
            int t = threadIdx.x + j * 256;
            s[t] += vals[j];
        }
        __syncthreads();
    }
    for (int t = threadIdx.x; t < 1024; t += 256) {
        int i = base + t;
        if (i < N) scanned[i] = s[t];
    }
    if (threadIdx.x == 0) bsums[blockIdx.x] = s[1023];
}

__global__ void k_scan_carry(int* bsums, int nb) {
    __shared__ int s[256];
    int t = threadIdx.x;
    s[t] = (t < nb) ? bsums[t] : 0;
    __syncthreads();
    for (int d = 1; d < 256; d <<= 1) {
        int v = (t >= d) ? s[t - d] : 0;
        __syncthreads();
        s[t] += v;
        __syncthreads();
    }
    if (t < nb) bsums[t] = s[t];
}

__global__ void k_scan_off(const int* __restrict__ scanned, const int* __restrict__ bsums,
                           int* __restrict__ off, int N) {
    int i = blockIdx.x * 256 + threadIdx.x;
    if (i > N) return;
    int v = 0;
    if (i > 0) {
        int j = i - 1;
        int b = j >> 10;
        v = scanned[j] + (b > 0 ? bsums[b - 1] : 0);
    }
    off[i] = v;
}

// ---------------- pass A scatter: partition edges by top digit (no global atomics) ----------------
__global__ __launch_bounds__(256) void k_scatter(const int* __restrict__ key, const int* __restrict__ val,
                                                 const int* __restrict__ off_flat, int2* __restrict__ tmp,
                                                 int E, int chunk, int shift) {
    __shared__ int cnt[ND];
    for (int t = threadIdx.x; t < ND; t += 256) cnt[t] = 0;
    __syncthreads();
    int b = blockIdx.x;
    int e0 = b * chunk, e1 = min(E, e0 + chunk);
    for (int e = e0 + threadIdx.x; e < e1; e += 256) {
        int k = key[e];
        int d = k >> shift;
        int r = atomicAdd(&cnt[d], 1);           // LDS-only rank
        tmp[off_flat[d * NB + b] + r] = make_int2(k, val[e]);
    }
}

// ---------------- pass B: per-bucket counting sort -> adj + node offsets ----------------
template <int WIDTH>
__global__ __launch_bounds__(256) void k_bucket(const int2* __restrict__ tmp,
                                                const int* __restrict__ off_flat,
                                                int* __restrict__ adj, int* __restrict__ off_node,
                                                int E, int shift, int NN) {
    __shared__ int cnt[WIDTH];
    int d = blockIdx.x;
    int bstart = off_flat[d * NB];
    int bend   = off_flat[(d + 1) * NB];
    for (int t = threadIdx.x; t < WIDTH; t += 256) cnt[t] = 0;
    __syncthreads();
    int bsz = bend - bstart;
    for (int i = threadIdx.x; i < bsz; i += 256)
        atomicAdd(&cnt[tmp[bstart + i].x & (WIDTH - 1)], 1);
    __syncthreads();
    int lane = threadIdx.x;
    if (lane < 64) {
        constexpr int EPL = WIDTH >> 6;
        int vals[EPL];
        int tot = 0;
        #pragma unroll
        for (int j = 0; j < EPL; ++j) { vals[j] = cnt[lane * EPL + j]; tot += vals[j]; }
        int inc = tot;
        #pragma unroll
        for (int o = 1; o < 64; o <<= 1) {
            int tsh = __shfl_up(inc, o, 64);
            if (lane >= o) inc += tsh;
        }
        int ex = inc - tot;
        #pragma unroll
        for (int j = 0; j < EPL; ++j) { cnt[lane * EPL + j] = ex; ex += vals[j]; }
    }
    __syncthreads();
    int base_node = d << shift;
    for (int t = threadIdx.x; t < WIDTH; t += 256) {
        int node = base_node + t;
        if (node < NN) off_node[node] = bstart + cnt[t];
    }
    if (d == 0 && threadIdx.x == 0) off_node[NN] = E;
    __syncthreads();
    for (int i = threadIdx.x; i < bsz; i += 256) {
        int2 e = tmp[bstart + i];
        int r = atomicAdd(&cnt[e.x & (WIDTH - 1)], 1);
        adj[bstart + r] = e.y;
    }
}

// ---------------- movie projection: relu(movie_x @ proj_w + b), transposed weights ----------------
__global__ __launch_bounds__(256, 2) void k_proj(const float* __restrict__ mx,
                                                 const float* __restrict__ w,
                                                 const float* __restrict__ b,
                                                 float* __restrict__ out, int M) {
    __shared__ float4 wt[64 * 64];      // wt[k4*64+lane] = {w[4k4+j][lane]}, 64 KB
    __shared__ float xs[16][256];       // 16 KB
    for (int t = threadIdx.x; t < 4096; t += 256) {
        int lane_i = t & 63, k4 = t >> 6, kb = k4 * 4;
        wt[t] = make_float4(w[(kb + 0) * 64 + lane_i], w[(kb + 1) * 64 + lane_i],
                            w[(kb + 2) * 64 + lane_i], w[(kb + 3) * 64 + lane_i]);
    }
    __syncthreads();
    int wid = threadIdx.x >> 6, lane = threadIdx.x & 63;
    int r0 = wid * 4;
    float bias = b[lane];
    for (int n0 = blockIdx.x * 16; n0 < M; n0 += gridDim.x * 16) {
        #pragma unroll
        for (int rr = 0; rr < 4; ++rr) {
            int n = n0 + r0 + rr;
            if (n < M)
                ((float4*)&xs[r0 + rr][0])[lane] = ((const float4*)mx)[(size_t)n * 64 + lane];
        }
        float a0 = bias, a1 = bias, a2 = bias, a3 = bias;
        #pragma unroll 2
        for (int k4 = 0; k4 < 64; ++k4) {
            float4 wv = wt[k4 * 64 + lane];
            float4 x0 = *(const float4*)&xs[r0 + 0][k4 * 4];
            float4 x1 = *(const float4*)&xs[r0 + 1][k4 * 4];
            float4 x2 = *(const float4*)&xs[r0 + 2][k4 * 4];
            float4 x3 = *(const float4*)&xs[r0 + 3][k4 * 4];
            #pragma unroll
            for (int j = 0; j < 4; ++j) {
                float wvj = (&wv.x)[j];
                a0 += (&x0.x)[j] * wvj;
                a1 += (&x1.x)[j] * wvj;
                a2 += (&x2.x)[j] * wvj;
                a3 += (&x3.x)[j] * wvj;
            }
        }
        int n = n0 + r0;
        if (n + 0 < M) out[(size_t)(n + 0) * 64 + lane] = fmaxf(a0, 0.f);
        if (n + 1 < M) out[(size_t)(n + 1) * 64 + lane] = fmaxf(a1, 0.f);
        if (n + 2 < M) out[(size_t)(n + 2) * 64 + lane] = fmaxf(a2, 0.f);
        if (n + 3 < M) out[(size_t)(n + 3) * 64 + lane] = fmaxf(a3, 0.f);
    }
}

// ---------------- gather-side segment mean: one wave per node, 4 rows in flight ----------------
__global__ __launch_bounds__(256) void k_agg(const float* __restrict__ x,
                                             const int* __restrict__ adj,
                                             const int* __restrict__ off,
                                             float* __restrict__ out, int N) {
    int node = blockIdx.x * 4 + (threadIdx.x >> 6);
    if (node >= N) return;
    int lane = threadIdx.x & 63;
    int g = lane >> 4, i = lane & 15;
    int s0 = off[node], s1 = off[node + 1];
    float4 a = make_float4(0.f, 0.f, 0.f, 0.f);
    float4 b = make_float4(0.f, 0.f, 0.f, 0.f);
    int e = s0 + g;
    for (; e + 4 < s1; e += 8) {
        float4 v = ((const float4*)x)[(size_t)adj[e] * 16 + i];
        float4 w = ((const float4*)x)[(size_t)adj[e + 4] * 16 + i];
        a.x += v.x; a.y += v.y; a.z += v.z; a.w += v.w;
        b.x += w.x; b.y += w.y; b.z += w.z; b.w += w.w;
    }
    if (e < s1) {
        float4 v = ((const float4*)x)[(size_t)adj[e] * 16 + i];
        a.x += v.x; a.y += v.y; a.z += v.z; a.w += v.w;
    }
    a.x += b.x; a.y += b.y; a.z += b.z; a.w += b.w;
    #pragma unroll
    for (int o = 16; o <= 32; o <<= 1) {
        a.x += __shfl_xor(a.x, o, 64);
        a.y += __shfl_xor(a.y, o, 64);
        a.z += __shfl_xor(a.z, o, 64);
        a.w += __shfl_xor(a.w, o, 64);
    }
    int deg = s1 - s0;
    float scale = (deg > 0) ? 1.0f / (float)deg : 0.f;
    if (g == 0) {
        float4 r = make_float4(a.x * scale, a.y * scale, a.z * scale, a.w * scale);
        ((float4*)out)[(size_t)node * 16 + i] = r;
    }
}

// ---------------- layer-1 transform via MFMA (f16 in, f32 acc) ----------------
// res = self + relu([mean|self] @ [wl;wr] + bl)
// A-frag: A[lane&15][8*(lane>>4)+j]; B-frag: B[8*(lane>>4)+j][lane&15];
// C/D: col=lane&15, row=(lane>>4)*4+reg  [verified mapping]
__global__ __launch_bounds__(256, 4) void k_trans1_mfma(const float* __restrict__ mean,
                                                        const float* __restrict__ self,
                                                        const float* __restrict__ wl,
                                                        const float* __restrict__ bl,
                                                        const float* __restrict__ wr,
                                                        float* __restrict__ res, int N) {
    __shared__ f16x8 wf[16 * 64];            // [kt*4+nt][lane] fragments, 16 KB
    __shared__ _Float16 xs[64][136];         // [node][k(128)]+8 pad, 17 KB
    const int tid = threadIdx.x;
    // stage fragmented weights: W = [wl; wr] (128 x 64)
    for (int idx = tid; idx < 1024; idx += 256) {
        int lane_i = idx & 63, t = idx >> 6;
        int kt = t >> 2, nt = t & 3;
        int col = nt * 16 + (lane_i & 15);
        int krow = kt * 32 + ((lane_i >> 4) << 3);
        f16x8 v;
        #pragma unroll
        for (int j = 0; j < 8; ++j) {
            int k = krow + j;
            const float* W = (k < 64) ? (wl + (size_t)k * 64) : (wr + (size_t)(k - 64) * 64);
            v[j] = (_Float16)W[col];
        }
        wf[t * 64 + lane_i] = v;
    }
    __syncthreads();
    const int w = tid >> 6, lane = tid & 63;
    const int g = lane >> 4, c15 = lane & 15;
    const int w16 = w * 16;
    float blv[4];
    #pragma unroll
    for (int nt = 0; nt < 4; ++nt) blv[nt] = bl[nt * 16 + c15];
    for (int n0 = blockIdx.x * 64; n0 < N; n0 += gridDim.x * 64) {
        // wave-private stage of 16 node rows as f16 [mean | self]
        for (int idx = lane; idx < 1024; idx += 64) {
            int i = idx >> 6, p = idx & 63;
            int n = n0 + w16 + i;
            float2 v = make_float2(0.f, 0.f);
            if (n < N)
                v = (p < 32) ? *(const float2*)&mean[(size_t)n * 64 + 2 * p]
                             : *(const float2*)&self[(size_t)n * 64 + 2 * (p - 32)];
            *(f16x2*)&xs[w16 + i][2 * p] = f16x2{(_Float16)v.x, (_Float16)v.y};
        }
        f32x4 acc[4];
        #pragma unroll
        for (int nt = 0; nt < 4; ++nt) acc[nt] = f32x4{0.f, 0.f, 0.f, 0.f};
        #pragma unroll
        for (int kt = 0; kt < 4; ++kt) {
            f16x8 af = *(const f16x8*)&xs[w16 + c15][kt * 32 + (g << 3)];
            #pragma unroll
            for (int nt = 0; nt < 4; ++nt)
                acc[nt] = __builtin_amdgcn_mfma_f32_16x16x32_f16(af, wf[(kt * 4 + nt) * 64 + lane],
                                                                 acc[nt], 0, 0, 0);
        }
        // epilogue: res = self(fp32) + relu(acc + bl)
        #pragma unroll
        for (int nt = 0; nt < 4; ++nt) {
            #pragma unroll
            for (int r = 0; r < 4; ++r) {
                int n = n0 + w16 + g * 4 + r;
                if (n < N) {
                    size_t o = (size_t)n * 64 + nt * 16 + c15;
                    res[o] = self[o] + fmaxf(acc[nt][r] + blv[nt], 0.f);
                }
            }
        }
    }
}

// ---------------- layer-2 transform + l2norm + decoder half-projection via MFMA ----------------
// u2 = [mean|res] @ [wl;wr] + bl ; A = (u2/max(||u2||,1e-12)) @ wd
// NOTE: outA may alias mean (in-place, row-exclusive) -> no __restrict__ on those.
__global__ __launch_bounds__(256, 4) void k_trans2_mfma(const float* mean,
                                                        const float* __restrict__ res,
                                                        const float* wl, const float* bl,
                                                        const float* wr, const float* wd,
                                                        float* outA, int N) {
    __shared__ f16x8 wf[16 * 64];            // [wl;wr] fragments, 16 KB
    __shared__ f16x8 wf2[8 * 64];            // wd fragments (K=64), 8 KB
    __shared__ _Float16 xs[64][136];         // [node][k(128)]+pad, 17 KB
    __shared__ _Float16 xs2[64][72];         // normalized u2, [node][k(64)]+pad, 9 KB
    const int tid = threadIdx.x;
    for (int idx = tid; idx < 1024; idx += 256) {
        int lane_i = idx & 63, t = idx >> 6;
        int kt = t >> 2, nt = t & 3;
        int col = nt * 16 + (lane_i & 15);
        int krow = kt * 32 + ((lane_i >> 4) << 3);
        f16x8 v;
        #pragma unroll
        for (int j = 0; j < 8; ++j) {
            int k = krow + j;
            const float* W = (k < 64) ? (wl + (size_t)k * 64) : (wr + (size_t)(k - 64) * 64);
            v[j] = (_Float16)W[col];
        }
        wf[t * 64 + lane_i] = v;
    }
    for (int idx = tid; idx < 512; idx += 256) {
        int lane_i = idx & 63, t = idx >> 6;
        int col = (t & 3) * 16 + (lane_i & 15);
        int krow = (t >> 2) * 32 + ((lane_i >> 4) << 3);
        f16x8 v;
        #pragma unroll
        for (int j = 0; j < 8; ++j)
            v[j] = (_Float16)wd[(size_t)(krow + j) * 64 + col];
        wf2[t * 64 + lane_i] = v;
    }
    __syncthreads();
    const int w = tid >> 6, lane = tid & 63;
    const int g = lane >> 4, c15 = lane & 15;
    const int w16 = w * 16;
    float blv[4];
    #pragma unroll
    for (int nt = 0; nt < 4; ++nt) blv[nt] = bl[nt * 16 + c15];
    for (int n0 = blockIdx.x * 64; n0 < N; n0 += gridDim.x * 64) {
        for (int idx = lane; idx < 1024; idx += 64) {
            int i = idx >> 6, p = idx & 63;
            int n = n0 + w16 + i;
            float2 v = make_float2(0.f, 0.f);
            if (n < N)
                v = (p < 32) ? *(const float2*)&mean[(size_t)n * 64 + 2 * p]
                             : *(const float2*)&res[(size_t)n * 64 + 2 * (p - 32)];
            *(f16x2*)&xs[w16 + i][2 * p] = f16x2{(_Float16)v.x, (_Float16)v.y};
        }
        f32x4 acc[4];
        #pragma unroll
        for (int nt = 0; nt < 4; ++nt) acc[nt] = f32x4{0.f, 0.f, 0.f, 0.f};
        #pragma unroll
        for (int kt = 0; kt < 4; ++kt) {
            f16x8 af = *(const f16x8*)&xs[w16 + c15][kt * 32 + (g << 3)];
            #pragma unroll
            for (int nt = 0; nt < 4; ++nt)
                acc[nt] = __builtin_amdgcn_mfma_f32_16x16x32_f16(af, wf[(kt * 4 + nt) * 64 + lane],
                                                                 acc[nt], 0, 0, 0);
        }
        // bias + per-row l2 norm (row sum over the 16 lanes of this group x 4 nt-tiles)
        float u2[4][4];
        #pragma unroll
        for (int nt = 0; nt < 4; ++nt)
            #pragma unroll
            for (int r = 0; r < 4; ++r)
                u2[nt][r] = acc[nt][r] + blv[nt];
        float sc[4];
        #pragma unroll
        for (int r = 0; r < 4; ++r) {
            float q = u2[0][r] * u2[0][r] + u2[1][r] * u2[1][r]
                    + u2[2][r] * u2[2][r] + u2[3][r] * u2[3][r];
            q += __shfl_xor(q, 1, 64);
            q += __shfl_xor(q, 2, 64);
            q += __shfl_xor(q, 4, 64);
            q += __shfl_xor(q, 8, 64);
            sc[r] = 1.f / fmaxf(sqrtf(q), 1e-12f);
        }
        // write normalized u2 to LDS (own group's rows only; wave-exclusive region)
        #pragma unroll
        for (int nt = 0; nt < 4; ++nt)
            #pragma unroll
            for (int r = 0; r < 4; ++r)
                xs2[w16 + g * 4 + r][nt * 16 + c15] = (_Float16)(u2[nt][r] * sc[r]);
        f32x4 acc2[4];
        #pragma unroll
        for (int nt = 0; nt < 4; ++nt) acc2[nt] = f32x4{0.f, 0.f, 0.f, 0.f};
        #pragma unroll
        for (int kt = 0; kt < 2; ++kt) {
            f16x8 af = *(const f16x8*)&xs2[w16 + c15][kt * 32 + (g << 3)];
            #pragma unroll
            for (int nt = 0; nt < 4; ++nt)
                acc2[nt] = __builtin_amdgcn_mfma_f32_16x16x32_f16(af, wf2[(kt * 4 + nt) * 64 + lane],
                                                                  acc2[nt], 0, 0, 0);
        }
        #pragma unroll
        for (int nt = 0; nt < 4; ++nt) {
            #pragma unroll
            for (int r = 0; r < 4; ++r) {
                int n = n0 + w16 + g * 4 + r;
                if (n < N)
                    outA[(size_t)n * 64 + nt * 16 + c15] = acc2[nt][r];
            }
        }
    }
}

// ---------------- decoder: out = relu(A[ls]+B[ld]+b1) . w2 + b2  (4 edges/wave) ----------------
__global__ __launch_bounds__(256) void k_dec(const float* __restrict__ A,
                                             const float* __restrict__ B,
                                             const int* __restrict__ ls,
                                             const int* __restrict__ ld,
                                             const float* __restrict__ b1,
                                             const float* __restrict__ w2,
                                             const float* __restrict__ b2,
                                             float* __restrict__ out, int EL) {
    int lane = threadIdx.x & 63;
    int g = lane >> 4, i = lane & 15;
    int e = blockIdx.x * 16 + (threadIdx.x >> 6) * 4 + g;
    if (e >= EL) return;
    int u = ls[e], m = ld[e];
    float4 av  = ((const float4*)A)[(size_t)u * 16 + i];
    float4 bv  = ((const float4*)B)[(size_t)m * 16 + i];
    float4 b1v = ((const float4*)b1)[i];
    float4 w2v = ((const float4*)w2)[i];
    float p = fmaxf(av.x + bv.x + b1v.x, 0.f) * w2v.x
            + fmaxf(av.y + bv.y + b1v.y, 0.f) * w2v.y
            + fmaxf(av.z + bv.z + b1v.z, 0.f) * w2v.z
            + fmaxf(av.w + bv.w + b1v.w, 0.f) * w2v.w;
    #pragma unroll
    for (int o = 1; o <= 8; o <<= 1) p += __shfl_xor(p, o, 64);
    if (i == 0) out[e] = p + b2[0];
}

extern "C" void kernel_launch(void* const* d_in, const int* in_sizes, int n_in,
                              void* d_out, int out_size, void* d_ws, size_t ws_size,
                              hipStream_t stream) {
    const float* movie_x  = (const float*)d_in[0];
    const float* user_emb = (const float*)d_in[1];
    const float* proj_w   = (const float*)d_in[2];
    const float* proj_b   = (const float*)d_in[3];
    const float* c1_um_wl = (const float*)d_in[4];
    const float* c1_um_bl = (const float*)d_in[5];
    const float* c1_um_wr = (const float*)d_in[6];
    const float* c1_mu_wl = (const float*)d_in[7];
    const float* c1_mu_bl = (const float*)d_in[8];
    const float* c1_mu_wr = (const float*)d_in[9];
    const float* c2_um_wl = (const float*)d_in[10];
    const float* c2_um_bl = (const float*)d_in[11];
    const float* c2_um_wr = (const float*)d_in[12];
    const float* c2_mu_wl = (const float*)d_in[13];
    const float* c2_mu_bl = (const float*)d_in[14];
    const float* c2_mu_wr = (const float*)d_in[15];
    const float* dec_w1   = (const float*)d_in[16];
    const float* dec_b1   = (const float*)d_in[17];
    const float* dec_w2   = (const float*)d_in[18];
    const float* dec_b2   = (const float*)d_in[19];
    const int* edge_src = (const int*)d_in[20];
    const int* edge_dst = (const int*)d_in[21];
    const int* lbl_src  = (const int*)d_in[22];
    const int* lbl_dst  = (const int*)d_in[23];

    const int M  = in_sizes[0] / 256;
    const int U  = in_sizes[1] / 64;
    const int E  = in_sizes[20];
    const int EL = in_sizes[22];
    float* out = (float*)d_out;

    char* ws = (char*)d_ws;
    size_t off = 0;
    auto alloc = [&](size_t bytes) -> void* {
        off = (off + 255) & ~(size_t)255;
        void* p = ws + off;
        off += bytes;
        return p;
    };
    int* bsums  = (int*)alloc(1024);
    int* off_u  = (int*)alloc((size_t)(U + 1) * 4);
    int* off_m  = (int*)alloc((size_t)(M + 1) * 4);
    int* adj_u  = (int*)alloc((size_t)E * 4);
    int* adj_m  = (int*)alloc((size_t)E * 4);
    float* movie0 = (float*)alloc((size_t)M * 64 * 4);   // later reused as B
    float* mean_m = (float*)alloc((size_t)M * 64 * 4);
    float* mean_u = (float*)alloc((size_t)U * 64 * 4);   // later reused as A (in-place)
    float* m_res  = (float*)alloc((size_t)M * 64 * 4);
    float* u_res  = (float*)alloc((size_t)U * 64 * 4);

    // CSR-build scratch aliases (all dead before mean_m/mean_u first written):
    int*  hist_u   = (int*)mean_m;            // ND*NB ints = 256 KB
    int*  hist_m   = hist_u + ND * NB;        // 256 KB
    int*  scanned  = hist_m + ND * NB;        // 256 KB
    int*  off_flat = scanned + ND * NB;       // ND*NB+1 ints
    int2* tmp      = (int2*)mean_u;           // E*8 = 16 MB (< 25.6 MB)

    auto cdiv = [](int a, int b) { return (a + b - 1) / b; };
    const int chunk = cdiv(E, NB);
    const int NF = ND * NB;                   // 65536 flat counters

    hipMemsetAsync(hist_u, 0, (size_t)NF * 4, stream);
    hipMemsetAsync(hist_m, 0, (size_t)NF * 4, stream);
    k_hist2<<<NB, 256, 0, stream>>>(edge_src, edge_dst, hist_u, hist_m, E, chunk);

    // movie-side CSR (bucket by dst>>7, width 128)
    k_scan_local<<<NF / 1024, 256, 0, stream>>>(hist_m, scanned, bsums, NF);
    k_scan_carry<<<1, 256, 0, stream>>>(bsums, NF / 1024);
    k_scan_off<<<cdiv(NF + 1, 256), 256, 0, stream>>>(scanned, bsums, off_flat, NF);
    k_scatter<<<NB, 256, 0, stream>>>(edge_dst, edge_src, off_flat, tmp, E, chunk, 7);
    k_bucket<128><<<ND, 256, 0, stream>>>(tmp, off_flat, adj_m, off_m, E, 7, M);

    // user-side CSR (bucket by src>>9, width 512)
    k_scan_local<<<NF / 1024, 256, 0, stream>>>(hist_u, scanned, bsums, NF);
    k_scan_carry<<<1, 256, 0, stream>>>(bsums, NF / 1024);
    k_scan_off<<<cdiv(NF + 1, 256), 256, 0, stream>>>(scanned, bsums, off_flat, NF);
    k_scatter<<<NB, 256, 0, stream>>>(edge_src, edge_dst, off_flat, tmp, E, chunk, 9);
    k_bucket<512><<<ND, 256, 0, stream>>>(tmp, off_flat, adj_u, off_u, E, 9, U);

    k_proj<<<cdiv(M, 16), 256, 0, stream>>>(movie_x, proj_w, proj_b, movie0, M);

    int gm = min(cdiv(M, 64), 2048);
    int gu = min(cdiv(U, 64), 2048);

    // layer 1
    k_agg<<<cdiv(M, 4), 256, 0, stream>>>(user_emb, adj_m, off_m, mean_m, M);
    k_agg<<<cdiv(U, 4), 256, 0, stream>>>(movie0, adj_u, off_u, mean_u, U);
    k_trans1_mfma<<<gm, 256, 0, stream>>>(mean_m, movie0, c1_um_wl, c1_um_bl, c1_um_wr, m_res, M);
    k_trans1_mfma<<<gu, 256, 0, stream>>>(mean_u, user_emb, c1_mu_wl, c1_mu_bl, c1_mu_wr, u_res, U);

    // layer 2
    k_agg<<<cdiv(M, 4), 256, 0, stream>>>(u_res, adj_m, off_m, mean_m, M);
    k_agg<<<cdiv(U, 4), 256, 0, stream>>>(m_res, adj_u, off_u, mean_u, U);
    // B = l2norm(m2) @ W1_bot   (into movie0 buffer)
    k_trans2_mfma<<<gm, 256, 0, stream>>>(mean_m, m_res, c2_um_wl, c2_um_bl, c2_um_wr,
                                          dec_w1 + 64 * 64, movie0, M);
    // A = l2norm(u2) @ W1_top   (in-place into mean_u)
    k_trans2_mfma<<<gu, 256, 0, stream>>>(mean_u, u_res, c2_mu_wl, c2_mu_bl, c2_mu_wr,
                                          dec_w1, mean_u, U);

    // decoder
    k_dec<<<cdiv(EL, 16), 256, 0, stream>>>(mean_u, movie0, lbl_src, lbl_dst,
                                            dec_b1, dec_w2, dec_b2, out, EL);
}

// Round 11
// 474.491 us; speedup vs baseline: 1.2207x; 1.0873x over previous
//
#include <hip/hip_runtime.h>

#define NB 256   // blocks for hist/scatter passes
#define ND 256   // digit buckets

typedef _Float16 f16x8 __attribute__((ext_vector_type(8)));
typedef _Float16 f16x4 __attribute__((ext_vector_type(4)));
typedef _Float16 f16x2 __attribute__((ext_vector_type(2)));
typedef float f32x4 __attribute__((ext_vector_type(4)));

// ---------------- fp32 -> fp16 row conversion ----------------
__global__ __launch_bounds__(256) void k_cvt(const float* __restrict__ in,
                                             _Float16* __restrict__ out, int n4) {
    int i = blockIdx.x * 256 + threadIdx.x;
    if (i < n4) {
        float4 v = ((const float4*)in)[i];
        ((f16x4*)out)[i] = f16x4{(_Float16)v.x, (_Float16)v.y, (_Float16)v.z, (_Float16)v.w};
    }
}

// ---------------- pass A: per-block digit histograms for BOTH sides ----------------
__global__ __launch_bounds__(256) void k_hist2(const int* __restrict__ src, const int* __restrict__ dst,
                                               int* __restrict__ hist_u, int* __restrict__ hist_m,
                                               int E, int chunk) {
    __shared__ int hu[ND], hm[ND];
    for (int t = threadIdx.x; t < ND; t += 256) { hu[t] = 0; hm[t] = 0; }
    __syncthreads();
    int b = blockIdx.x;
    int e0 = b * chunk, e1 = min(E, e0 + chunk);
    for (int e = e0 + threadIdx.x; e < e1; e += 256) {
        atomicAdd(&hu[src[e] >> 9], 1);
        atomicAdd(&hm[dst[e] >> 7], 1);
    }
    __syncthreads();
    for (int t = threadIdx.x; t < ND; t += 256) {
        hist_u[t * NB + b] = hu[t];
        hist_m[t * NB + b] = hm[t];
    }
}

// ---------------- 2-level inclusive scan -> exclusive offsets ----------------
__global__ void k_scan_local(const int* __restrict__ deg, int* __restrict__ scanned,
                             int* __restrict__ bsums, int N) {
    __shared__ int s[1024];
    int base = blockIdx.x * 1024;
    for (int t = threadIdx.x; t < 1024; t += 256) {
        int i = base + t;
        s[t] = (i < N) ? deg[i] : 0;
    }
    __syncthreads();
    for (int d = 1; d < 1024; d <<= 1) {
        int vals[4];
        for (int j = 0; j < 4; ++j) {
            int t = threadIdx.x + j * 256;
            vals[j] = (t >= d) ? s[t - d] : 0;
        }
        __syncthreads();
        for (int j = 0; j < 4; ++j) {
            int t = threadIdx.x + j * 256;
            s[t] += vals[j];
        }
        __syncthreads();
    }
    for (int t = threadIdx.x; t < 1024; t += 256) {
        int i = base + t;
        if (i < N) scanned[i] = s[t];
    }
    if (threadIdx.x == 0) bsums[blockIdx.x] = s[1023];
}

__global__ void k_scan_carry(int* bsums, int nb) {
    __shared__ int s[256];
    int t = threadIdx.x;
    s[t] = (t < nb) ? bsums[t] : 0;
    __syncthreads();
    for (int d = 1; d < 256; d <<= 1) {
        int v = (t >= d) ? s[t - d] : 0;
        __syncthreads();
        s[t] += v;
        __syncthreads();
    }
    if (t < nb) bsums[t] = s[t];
}

__global__ void k_scan_off(const int* __restrict__ scanned, const int* __restrict__ bsums,
                           int* __restrict__ off, int N) {
    int i = blockIdx.x * 256 + threadIdx.x;
    if (i > N) return;
    int v = 0;
    if (i > 0) {
        int j = i - 1;
        int b = j >> 10;
        v = scanned[j] + (b > 0 ? bsums[b - 1] : 0);
    }
    off[i] = v;
}

// ---------------- pass A scatter: partition edges by top digit (no global atomics) ----------------
__global__ __launch_bounds__(256) void k_scatter(const int* __restrict__ key, const int* __restrict__ val,
                                                 const int* __restrict__ off_flat, int2* __restrict__ tmp,
                                                 int E, int chunk, int shift) {
    __shared__ int cnt[ND];
    for (int t = threadIdx.x; t < ND; t += 256) cnt[t] = 0;
    __syncthreads();
    int b = blockIdx.x;
    int e0 = b * chunk, e1 = min(E, e0 + chunk);
    for (int e = e0 + threadIdx.x; e < e1; e += 256) {
        int k = key[e];
        int d = k >> shift;
        int r = atomicAdd(&cnt[d], 1);           // LDS-only rank
        tmp[off_flat[d * NB + b] + r] = make_int2(k, val[e]);
    }
}

// ---------------- pass B: per-bucket counting sort -> adj + node offsets ----------------
template <int WIDTH>
__global__ __launch_bounds__(256) void k_bucket(const int2* __restrict__ tmp,
                                                const int* __restrict__ off_flat,
                                                int* __restrict__ adj, int* __restrict__ off_node,
                                                int E, int shift, int NN) {
    __shared__ int cnt[WIDTH];
    int d = blockIdx.x;
    int bstart = off_flat[d * NB];
    int bend   = off_flat[(d + 1) * NB];
    for (int t = threadIdx.x; t < WIDTH; t += 256) cnt[t] = 0;
    __syncthreads();
    int bsz = bend - bstart;
    for (int i = threadIdx.x; i < bsz; i += 256)
        atomicAdd(&cnt[tmp[bstart + i].x & (WIDTH - 1)], 1);
    __syncthreads();
    int lane = threadIdx.x;
    if (lane < 64) {
        constexpr int EPL = WIDTH >> 6;
        int vals[EPL];
        int tot = 0;
        #pragma unroll
        for (int j = 0; j < EPL; ++j) { vals[j] = cnt[lane * EPL + j]; tot += vals[j]; }
        int inc = tot;
        #pragma unroll
        for (int o = 1; o < 64; o <<= 1) {
            int tsh = __shfl_up(inc, o, 64);
            if (lane >= o) inc += tsh;
        }
        int ex = inc - tot;
        #pragma unroll
        for (int j = 0; j < EPL; ++j) { cnt[lane * EPL + j] = ex; ex += vals[j]; }
    }
    __syncthreads();
    int base_node = d << shift;
    for (int t = threadIdx.x; t < WIDTH; t += 256) {
        int node = base_node + t;
        if (node < NN) off_node[node] = bstart + cnt[t];
    }
    if (d == 0 && threadIdx.x == 0) off_node[NN] = E;
    __syncthreads();
    for (int i = threadIdx.x; i < bsz; i += 256) {
        int2 e = tmp[bstart + i];
        int r = atomicAdd(&cnt[e.x & (WIDTH - 1)], 1);
        adj[bstart + r] = e.y;
    }
}

// ---------------- movie projection: relu(movie_x @ proj_w + b); fp32 + f16 outputs ----------------
__global__ __launch_bounds__(256, 2) void k_proj(const float* __restrict__ mx,
                                                 const float* __restrict__ w,
                                                 const float* __restrict__ b,
                                                 float* __restrict__ out,
                                                 _Float16* __restrict__ out16, int M) {
    __shared__ float4 wt[64 * 64];      // wt[k4*64+lane] = {w[4k4+j][lane]}, 64 KB
    __shared__ float xs[16][256];       // 16 KB
    for (int t = threadIdx.x; t < 4096; t += 256) {
        int lane_i = t & 63, k4 = t >> 6, kb = k4 * 4;
        wt[t] = make_float4(w[(kb + 0) * 64 + lane_i], w[(kb + 1) * 64 + lane_i],
                            w[(kb + 2) * 64 + lane_i], w[(kb + 3) * 64 + lane_i]);
    }
    __syncthreads();
    int wid = threadIdx.x >> 6, lane = threadIdx.x & 63;
    int r0 = wid * 4;
    float bias = b[lane];
    for (int n0 = blockIdx.x * 16; n0 < M; n0 += gridDim.x * 16) {
        #pragma unroll
        for (int rr = 0; rr < 4; ++rr) {
            int n = n0 + r0 + rr;
            if (n < M)
                ((float4*)&xs[r0 + rr][0])[lane] = ((const float4*)mx)[(size_t)n * 64 + lane];
        }
        float a0 = bias, a1 = bias, a2 = bias, a3 = bias;
        #pragma unroll 2
        for (int k4 = 0; k4 < 64; ++k4) {
            float4 wv = wt[k4 * 64 + lane];
            float4 x0 = *(const float4*)&xs[r0 + 0][k4 * 4];
            float4 x1 = *(const float4*)&xs[r0 + 1][k4 * 4];
            float4 x2 = *(const float4*)&xs[r0 + 2][k4 * 4];
            float4 x3 = *(const float4*)&xs[r0 + 3][k4 * 4];
            #pragma unroll
            for (int j = 0; j < 4; ++j) {
                float wvj = (&wv.x)[j];
                a0 += (&x0.x)[j] * wvj;
                a1 += (&x1.x)[j] * wvj;
                a2 += (&x2.x)[j] * wvj;
                a3 += (&x3.x)[j] * wvj;
            }
        }
        int n = n0 + r0;
        float r[4] = {fmaxf(a0, 0.f), fmaxf(a1, 0.f), fmaxf(a2, 0.f), fmaxf(a3, 0.f)};
        #pragma unroll
        for (int rr = 0; rr < 4; ++rr) {
            if (n + rr < M) {
                out[(size_t)(n + rr) * 64 + lane] = r[rr];
                out16[(size_t)(n + rr) * 64 + lane] = (_Float16)r[rr];
            }
        }
    }
}

// ---------------- gather-side segment mean over f16 rows: one wave per node ----------------
__global__ __launch_bounds__(256) void k_agg_h(const _Float16* __restrict__ x,
                                               const int* __restrict__ adj,
                                               const int* __restrict__ off,
                                               float* __restrict__ out, int N) {
    int node = blockIdx.x * 4 + (threadIdx.x >> 6);
    if (node >= N) return;
    int lane = threadIdx.x & 63;
    int g = lane >> 4, i = lane & 15;
    int s0 = off[node], s1 = off[node + 1];
    float4 a = make_float4(0.f, 0.f, 0.f, 0.f);
    float4 b = make_float4(0.f, 0.f, 0.f, 0.f);
    int e = s0 + g;
    for (; e + 4 < s1; e += 8) {
        f16x4 v = ((const f16x4*)x)[(size_t)adj[e] * 16 + i];
        f16x4 w = ((const f16x4*)x)[(size_t)adj[e + 4] * 16 + i];
        a.x += (float)v[0]; a.y += (float)v[1]; a.z += (float)v[2]; a.w += (float)v[3];
        b.x += (float)w[0]; b.y += (float)w[1]; b.z += (float)w[2]; b.w += (float)w[3];
    }
    if (e < s1) {
        f16x4 v = ((const f16x4*)x)[(size_t)adj[e] * 16 + i];
        a.x += (float)v[0]; a.y += (float)v[1]; a.z += (float)v[2]; a.w += (float)v[3];
    }
    a.x += b.x; a.y += b.y; a.z += b.z; a.w += b.w;
    #pragma unroll
    for (int o = 16; o <= 32; o <<= 1) {
        a.x += __shfl_xor(a.x, o, 64);
        a.y += __shfl_xor(a.y, o, 64);
        a.z += __shfl_xor(a.z, o, 64);
        a.w += __shfl_xor(a.w, o, 64);
    }
    int deg = s1 - s0;
    float scale = (deg > 0) ? 1.0f / (float)deg : 0.f;
    if (g == 0) {
        float4 r = make_float4(a.x * scale, a.y * scale, a.z * scale, a.w * scale);
        ((float4*)out)[(size_t)node * 16 + i] = r;
    }
}

// ---------------- layer-1 transform via MFMA; f16 residual output ----------------
// res16 = f16( self + relu([mean|self] @ [wl;wr] + bl) )
__global__ __launch_bounds__(256, 4) void k_trans1_mfma(const float* __restrict__ mean,
                                                        const float* __restrict__ self,
                                                        const float* __restrict__ wl,
                                                        const float* __restrict__ bl,
                                                        const float* __restrict__ wr,
                                                        _Float16* __restrict__ res16, int N) {
    __shared__ f16x8 wf[16 * 64];            // [kt*4+nt][lane] fragments, 16 KB
    __shared__ _Float16 xs[64][136];         // [node][k(128)]+8 pad, 17 KB
    const int tid = threadIdx.x;
    for (int idx = tid; idx < 1024; idx += 256) {
        int lane_i = idx & 63, t = idx >> 6;
        int kt = t >> 2, nt = t & 3;
        int col = nt * 16 + (lane_i & 15);
        int krow = kt * 32 + ((lane_i >> 4) << 3);
        f16x8 v;
        #pragma unroll
        for (int j = 0; j < 8; ++j) {
            int k = krow + j;
            const float* W = (k < 64) ? (wl + (size_t)k * 64) : (wr + (size_t)(k - 64) * 64);
            v[j] = (_Float16)W[col];
        }
        wf[t * 64 + lane_i] = v;
    }
    __syncthreads();
    const int w = tid >> 6, lane = tid & 63;
    const int g = lane >> 4, c15 = lane & 15;
    const int w16 = w * 16;
    float blv[4];
    #pragma unroll
    for (int nt = 0; nt < 4; ++nt) blv[nt] = bl[nt * 16 + c15];
    for (int n0 = blockIdx.x * 64; n0 < N; n0 += gridDim.x * 64) {
        for (int idx = lane; idx < 1024; idx += 64) {
            int i = idx >> 6, p = idx & 63;
            int n = n0 + w16 + i;
            float2 v = make_float2(0.f, 0.f);
            if (n < N)
                v = (p < 32) ? *(const float2*)&mean[(size_t)n * 64 + 2 * p]
                             : *(const float2*)&self[(size_t)n * 64 + 2 * (p - 32)];
            *(f16x2*)&xs[w16 + i][2 * p] = f16x2{(_Float16)v.x, (_Float16)v.y};
        }
        f32x4 acc[4];
        #pragma unroll
        for (int nt = 0; nt < 4; ++nt) acc[nt] = f32x4{0.f, 0.f, 0.f, 0.f};
        #pragma unroll
        for (int kt = 0; kt < 4; ++kt) {
            f16x8 af = *(const f16x8*)&xs[w16 + c15][kt * 32 + (g << 3)];
            #pragma unroll
            for (int nt = 0; nt < 4; ++nt)
                acc[nt] = __builtin_amdgcn_mfma_f32_16x16x32_f16(af, wf[(kt * 4 + nt) * 64 + lane],
                                                                 acc[nt], 0, 0, 0);
        }
        #pragma unroll
        for (int nt = 0; nt < 4; ++nt) {
            #pragma unroll
            for (int r = 0; r < 4; ++r) {
                int n = n0 + w16 + g * 4 + r;
                if (n < N) {
                    size_t o = (size_t)n * 64 + nt * 16 + c15;
                    res16[o] = (_Float16)(self[o] + fmaxf(acc[nt][r] + blv[nt], 0.f));
                }
            }
        }
    }
}

// ---------------- layer-2 transform + l2norm + decoder half-projection via MFMA ----------------
// u2 = [mean|res16] @ [wl;wr] + bl ; A = (u2/max(||u2||,1e-12)) @ wd
// NOTE: outA may alias mean (in-place, row-exclusive) -> no __restrict__ on those.
__global__ __launch_bounds__(256, 4) void k_trans2_mfma(const float* mean,
                                                        const _Float16* __restrict__ res16,
                                                        const float* wl, const float* bl,
                                                        const float* wr, const float* wd,
                                                        float* outA, int N) {
    __shared__ f16x8 wf[16 * 64];            // [wl;wr] fragments, 16 KB
    __shared__ f16x8 wf2[8 * 64];            // wd fragments (K=64), 8 KB
    __shared__ _Float16 xs[64][136];         // [node][k(128)]+pad, 17 KB
    __shared__ _Float16 xs2[64][72];         // normalized u2, 9 KB
    const int tid = threadIdx.x;
    for (int idx = tid; idx < 1024; idx += 256) {
        int lane_i = idx & 63, t = idx >> 6;
        int kt = t >> 2, nt = t & 3;
        int col = nt * 16 + (lane_i & 15);
        int krow = kt * 32 + ((lane_i >> 4) << 3);
        f16x8 v;
        #pragma unroll
        for (int j = 0; j < 8; ++j) {
            int k = krow + j;
            const float* W = (k < 64) ? (wl + (size_t)k * 64) : (wr + (size_t)(k - 64) * 64);
            v[j] = (_Float16)W[col];
        }
        wf[t * 64 + lane_i] = v;
    }
    for (int idx = tid; idx < 512; idx += 256) {
        int lane_i = idx & 63, t = idx >> 6;
        int col = (t & 3) * 16 + (lane_i & 15);
        int krow = (t >> 2) * 32 + ((lane_i >> 4) << 3);
        f16x8 v;
        #pragma unroll
        for (int j = 0; j < 8; ++j)
            v[j] = (_Float16)wd[(size_t)(krow + j) * 64 + col];
        wf2[t * 64 + lane_i] = v;
    }
    __syncthreads();
    const int w = tid >> 6, lane = tid & 63;
    const int g = lane >> 4, c15 = lane & 15;
    const int w16 = w * 16;
    float blv[4];
    #pragma unroll
    for (int nt = 0; nt < 4; ++nt) blv[nt] = bl[nt * 16 + c15];
    for (int n0 = blockIdx.x * 64; n0 < N; n0 += gridDim.x * 64) {
        for (int idx = lane; idx < 1024; idx += 64) {
            int i = idx >> 6, p = idx & 63;
            int n = n0 + w16 + i;
            f16x2 h = f16x2{(_Float16)0.f, (_Float16)0.f};
            if (n < N) {
                if (p < 32) {
                    float2 v = *(const float2*)&mean[(size_t)n * 64 + 2 * p];
                    h = f16x2{(_Float16)v.x, (_Float16)v.y};
                } else {
                    h = *(const f16x2*)&res16[(size_t)n * 64 + 2 * (p - 32)];
                }
            }
            *(f16x2*)&xs[w16 + i][2 * p] = h;
        }
        f32x4 acc[4];
        #pragma unroll
        for (int nt = 0; nt < 4; ++nt) acc[nt] = f32x4{0.f, 0.f, 0.f, 0.f};
        #pragma unroll
        for (int kt = 0; kt < 4; ++kt) {
            f16x8 af = *(const f16x8*)&xs[w16 + c15][kt * 32 + (g << 3)];
            #pragma unroll
            for (int nt = 0; nt < 4; ++nt)
                acc[nt] = __builtin_amdgcn_mfma_f32_16x16x32_f16(af, wf[(kt * 4 + nt) * 64 + lane],
                                                                 acc[nt], 0, 0, 0);
        }
        float u2[4][4];
        #pragma unroll
        for (int nt = 0; nt < 4; ++nt)
            #pragma unroll
            for (int r = 0; r < 4; ++r)
                u2[nt][r] = acc[nt][r] + blv[nt];
        float sc[4];
        #pragma unroll
        for (int r = 0; r < 4; ++r) {
            float q = u2[0][r] * u2[0][r] + u2[1][r] * u2[1][r]
                    + u2[2][r] * u2[2][r] + u2[3][r] * u2[3][r];
            q += __shfl_xor(q, 1, 64);
            q += __shfl_xor(q, 2, 64);
            q += __shfl_xor(q, 4, 64);
            q += __shfl_xor(q, 8, 64);
            sc[r] = 1.f / fmaxf(sqrtf(q), 1e-12f);
        }
        #pragma unroll
        for (int nt = 0; nt < 4; ++nt)
            #pragma unroll
            for (int r = 0; r < 4; ++r)
                xs2[w16 + g * 4 + r][nt * 16 + c15] = (_Float16)(u2[nt][r] * sc[r]);
        f32x4 acc2[4];
        #pragma unroll
        for (int nt = 0; nt < 4; ++nt) acc2[nt] = f32x4{0.f, 0.f, 0.f, 0.f};
        #pragma unroll
        for (int kt = 0; kt < 2; ++kt) {
            f16x8 af = *(const f16x8*)&xs2[w16 + c15][kt * 32 + (g << 3)];
            #pragma unroll
            for (int nt = 0; nt < 4; ++nt)
                acc2[nt] = __builtin_amdgcn_mfma_f32_16x16x32_f16(af, wf2[(kt * 4 + nt) * 64 + lane],
                                                                  acc2[nt], 0, 0, 0);
        }
        #pragma unroll
        for (int nt = 0; nt < 4; ++nt) {
            #pragma unroll
            for (int r = 0; r < 4; ++r) {
                int n = n0 + w16 + g * 4 + r;
                if (n < N)
                    outA[(size_t)n * 64 + nt * 16 + c15] = acc2[nt][r];
            }
        }
    }
}

// ---------------- decoder: out = relu(A[ls]+B[ld]+b1) . w2 + b2  (4 edges/wave) ----------------
__global__ __launch_bounds__(256) void k_dec(const float* __restrict__ A,
                                             const float* __restrict__ B,
                                             const int* __restrict__ ls,
                                             const int* __restrict__ ld,
                                             const float* __restrict__ b1,
                                             const float* __restrict__ w2,
                                             const float* __restrict__ b2,
                                             float* __restrict__ out, int EL) {
    int lane = threadIdx.x & 63;
    int g = lane >> 4, i = lane & 15;
    int e = blockIdx.x * 16 + (threadIdx.x >> 6) * 4 + g;
    if (e >= EL) return;
    int u = ls[e], m = ld[e];
    float4 av  = ((const float4*)A)[(size_t)u * 16 + i];
    float4 bv  = ((const float4*)B)[(size_t)m * 16 + i];
    float4 b1v = ((const float4*)b1)[i];
    float4 w2v = ((const float4*)w2)[i];
    float p = fmaxf(av.x + bv.x + b1v.x, 0.f) * w2v.x
            + fmaxf(av.y + bv.y + b1v.y, 0.f) * w2v.y
            + fmaxf(av.z + bv.z + b1v.z, 0.f) * w2v.z
            + fmaxf(av.w + bv.w + b1v.w, 0.f) * w2v.w;
    #pragma unroll
    for (int o = 1; o <= 8; o <<= 1) p += __shfl_xor(p, o, 64);
    if (i == 0) out[e] = p + b2[0];
}

extern "C" void kernel_launch(void* const* d_in, const int* in_sizes, int n_in,
                              void* d_out, int out_size, void* d_ws, size_t ws_size,
                              hipStream_t stream) {
    const float* movie_x  = (const float*)d_in[0];
    const float* user_emb = (const float*)d_in[1];
    const float* proj_w   = (const float*)d_in[2];
    const float* proj_b   = (const float*)d_in[3];
    const float* c1_um_wl = (const float*)d_in[4];
    const float* c1_um_bl = (const float*)d_in[5];
    const float* c1_um_wr = (const float*)d_in[6];
    const float* c1_mu_wl = (const float*)d_in[7];
    const float* c1_mu_bl = (const float*)d_in[8];
    const float* c1_mu_wr = (const float*)d_in[9];
    const float* c2_um_wl = (const float*)d_in[10];
    const float* c2_um_bl = (const float*)d_in[11];
    const float* c2_um_wr = (const float*)d_in[12];
    const float* c2_mu_wl = (const float*)d_in[13];
    const float* c2_mu_bl = (const float*)d_in[14];
    const float* c2_mu_wr = (const float*)d_in[15];
    const float* dec_w1   = (const float*)d_in[16];
    const float* dec_b1   = (const float*)d_in[17];
    const float* dec_w2   = (const float*)d_in[18];
    const float* dec_b2   = (const float*)d_in[19];
    const int* edge_src = (const int*)d_in[20];
    const int* edge_dst = (const int*)d_in[21];
    const int* lbl_src  = (const int*)d_in[22];
    const int* lbl_dst  = (const int*)d_in[23];

    const int M  = in_sizes[0] / 256;
    const int U  = in_sizes[1] / 64;
    const int E  = in_sizes[20];
    const int EL = in_sizes[22];
    float* out = (float*)d_out;

    char* ws = (char*)d_ws;
    size_t off = 0;
    auto alloc = [&](size_t bytes) -> void* {
        off = (off + 255) & ~(size_t)255;
        void* p = ws + off;
        off += bytes;
        return p;
    };
    int* bsums  = (int*)alloc(1024);
    int* off_u  = (int*)alloc((size_t)(U + 1) * 4);
    int* off_m  = (int*)alloc((size_t)(M + 1) * 4);
    int* adj_u  = (int*)alloc((size_t)E * 4);
    int* adj_m  = (int*)alloc((size_t)E * 4);
    float* movie0 = (float*)alloc((size_t)M * 64 * 4);       // fp32, later reused as B
    _Float16* movie16 = (_Float16*)alloc((size_t)M * 64 * 2);
    _Float16* user16  = (_Float16*)alloc((size_t)U * 64 * 2);
    float* mean_m = (float*)alloc((size_t)M * 64 * 4);
    float* mean_u = (float*)alloc((size_t)U * 64 * 4);       // later reused as A (in-place)
    _Float16* m_res16 = (_Float16*)alloc((size_t)M * 64 * 2);
    _Float16* u_res16 = (_Float16*)alloc((size_t)U * 64 * 2);

    // CSR-build scratch aliases (all dead before mean_m/mean_u first written):
    int*  hist_u   = (int*)mean_m;            // ND*NB ints = 256 KB
    int*  hist_m   = hist_u + ND * NB;        // 256 KB
    int*  scanned  = hist_m + ND * NB;        // 256 KB
    int*  off_flat = scanned + ND * NB;       // ND*NB+1 ints
    int2* tmp      = (int2*)mean_u;           // E*8 = 16 MB (< 25.6 MB)

    auto cdiv = [](int a, int b) { return (a + b - 1) / b; };
    const int chunk = cdiv(E, NB);
    const int NF = ND * NB;                   // 65536 flat counters

    hipMemsetAsync(hist_u, 0, (size_t)NF * 4, stream);
    hipMemsetAsync(hist_m, 0, (size_t)NF * 4, stream);
    k_hist2<<<NB, 256, 0, stream>>>(edge_src, edge_dst, hist_u, hist_m, E, chunk);

    // user_emb -> f16 table (gather source for layer-1 movie-side agg)
    k_cvt<<<cdiv(U * 16, 256), 256, 0, stream>>>(user_emb, user16, U * 16);

    // movie-side CSR (bucket by dst>>7, width 128)
    k_scan_local<<<NF / 1024, 256, 0, stream>>>(hist_m, scanned, bsums, NF);
    k_scan_carry<<<1, 256, 0, stream>>>(bsums, NF / 1024);
    k_scan_off<<<cdiv(NF + 1, 256), 256, 0, stream>>>(scanned, bsums, off_flat, NF);
    k_scatter<<<NB, 256, 0, stream>>>(edge_dst, edge_src, off_flat, tmp, E, chunk, 7);
    k_bucket<128><<<ND, 256, 0, stream>>>(tmp, off_flat, adj_m, off_m, E, 7, M);

    // user-side CSR (bucket by src>>9, width 512)
    k_scan_local<<<NF / 1024, 256, 0, stream>>>(hist_u, scanned, bsums, NF);
    k_scan_carry<<<1, 256, 0, stream>>>(bsums, NF / 1024);
    k_scan_off<<<cdiv(NF + 1, 256), 256, 0, stream>>>(scanned, bsums, off_flat, NF);
    k_scatter<<<NB, 256, 0, stream>>>(edge_src, edge_dst, off_flat, tmp, E, chunk, 9);
    k_bucket<512><<<ND, 256, 0, stream>>>(tmp, off_flat, adj_u, off_u, E, 9, U);

    k_proj<<<cdiv(M, 16), 256, 0, stream>>>(movie_x, proj_w, proj_b, movie0, movie16, M);

    int gm = min(cdiv(M, 64), 2048);
    int gu = min(cdiv(U, 64), 2048);

    // layer 1 (gathers over f16 tables)
    k_agg_h<<<cdiv(M, 4), 256, 0, stream>>>(user16, adj_m, off_m, mean_m, M);
    k_agg_h<<<cdiv(U, 4), 256, 0, stream>>>(movie16, adj_u, off_u, mean_u, U);
    k_trans1_mfma<<<gm, 256, 0, stream>>>(mean_m, movie0, c1_um_wl, c1_um_bl, c1_um_wr, m_res16, M);
    k_trans1_mfma<<<gu, 256, 0, stream>>>(mean_u, user_emb, c1_mu_wl, c1_mu_bl, c1_mu_wr, u_res16, U);

    // layer 2 (gathers over f16 residuals)
    k_agg_h<<<cdiv(M, 4), 256, 0, stream>>>(u_res16, adj_m, off_m, mean_m, M);
    k_agg_h<<<cdiv(U, 4), 256, 0, stream>>>(m_res16, adj_u, off_u, mean_u, U);
    // B = l2norm(m2) @ W1_bot   (into movie0 buffer)
    k_trans2_mfma<<<gm, 256, 0, stream>>>(mean_m, m_res16, c2_um_wl, c2_um_bl, c2_um_wr,
                                          dec_w1 + 64 * 64, movie0, M);
    // A = l2norm(u2) @ W1_top   (in-place into mean_u)
    k_trans2_mfma<<<gu, 256, 0, stream>>>(mean_u, u_res16, c2_mu_wl, c2_mu_bl, c2_mu_wr,
                                          dec_w1, mean_u, U);

    // decoder
    k_dec<<<cdiv(EL, 16), 256, 0, stream>>>(mean_u, movie0, lbl_src, lbl_dst,
                                            dec_b1, dec_w2, dec_b2, out, EL);
}